// Round 2
// baseline (275.703 us; speedup 1.0000x reference)
//
#include <hip/hip_runtime.h>

// RoPE sin/cos table gather:
//   out[pos_idx, 2k]   = cache[p, k, 1]  (cos)
//   out[pos_idx, 2k+1] = cache[p, k, 0]  (sin)
// cache row is contiguous 512 floats: [sin0, cos0, sin1, cos1, ...]
// -> per-float4 pairwise swap, fully coalesced 16B/lane loads and stores.
//
// V3: DIAGNOSTIC ROUND — kernel body identical to V2 (ILP-batched, 4 pos /
// 32-thread group, 16 independent gathers + 16 NT stores per thread).
// kernel_launch fires the SAME kernel 4x back-to-back (bit-idempotent:
// identical writes, serialized on one stream, so output is unchanged and
// correctness is preserved).
//
// Purpose: dur_us ~= F + 4K (F = harness fill/memset floor, K = kernel time).
// Round 1 gave F + K ~= 162 us. The slope identifies K, which the rocprof
// top-5 (crowded out by 512 MiB poison fills at 82-85 us) cannot show:
//   K ~= 80 us  -> dur ~400 us  (kernel-dominant; attack kernel next)
//   K ~= 25-40  -> dur ~235-280 (kernel near its HBM-write roofline)
//   K <  5      -> dur <=175    (harness floor; declare roofline)

#define EMBED_DIM 512
#define POS_PER_GROUP 4              // positions handled per 32-thread group
#define N_LAUNCHES 4                 // diagnostic: measure slope dur/launch

typedef float v4f __attribute__((ext_vector_type(4)));
typedef int   v4i __attribute__((ext_vector_type(4)));

__device__ __forceinline__ v4f swap_pairs(v4f v) {
    // (sin0, cos0, sin1, cos1) -> (cos0, sin0, cos1, sin1)
    return (v4f){v.y, v.x, v.w, v.z};
}

__device__ __forceinline__ void do_one_pos(int sub, int p,
                                           const float* __restrict__ cache,
                                           float* __restrict__ dst_row) {
    const v4f* __restrict__ src = (const v4f*)(cache + (size_t)p * EMBED_DIM);
    v4f* __restrict__ dst       = (v4f*)dst_row;
    v4f v0 = src[sub];
    v4f v1 = src[sub + 32];
    v4f v2 = src[sub + 64];
    v4f v3 = src[sub + 96];
    __builtin_nontemporal_store(swap_pairs(v0), &dst[sub]);
    __builtin_nontemporal_store(swap_pairs(v1), &dst[sub + 32]);
    __builtin_nontemporal_store(swap_pairs(v2), &dst[sub + 64]);
    __builtin_nontemporal_store(swap_pairs(v3), &dst[sub + 96]);
}

__global__ __launch_bounds__(256) void ScalarRoPEEmbedding_83769042141635_kernel(
    const int* __restrict__ positions,
    const float* __restrict__ cache,
    float* __restrict__ out,
    int n_pos)
{
    int tid   = blockIdx.x * blockDim.x + threadIdx.x;
    int group = tid >> 5;            // which group of POS_PER_GROUP positions
    int sub   = tid & 31;            // lane-within-group: owns 4 float4 per row
    int base  = group * POS_PER_GROUP;
    if (base >= n_pos) return;

    if (base + POS_PER_GROUP <= n_pos) {
        // Fast path: one 16B load for all 4 indices (base % 4 == 0 -> aligned).
        v4i p4 = *(const v4i*)(positions + base);

        const v4f* __restrict__ s0 = (const v4f*)(cache + (size_t)p4.x * EMBED_DIM);
        const v4f* __restrict__ s1 = (const v4f*)(cache + (size_t)p4.y * EMBED_DIM);
        const v4f* __restrict__ s2 = (const v4f*)(cache + (size_t)p4.z * EMBED_DIM);
        const v4f* __restrict__ s3 = (const v4f*)(cache + (size_t)p4.w * EMBED_DIM);

        // 16 independent loads in flight.
        v4f a00 = s0[sub], a01 = s0[sub + 32], a02 = s0[sub + 64], a03 = s0[sub + 96];
        v4f a10 = s1[sub], a11 = s1[sub + 32], a12 = s1[sub + 64], a13 = s1[sub + 96];
        v4f a20 = s2[sub], a21 = s2[sub + 32], a22 = s2[sub + 64], a23 = s2[sub + 96];
        v4f a30 = s3[sub], a31 = s3[sub + 32], a32 = s3[sub + 64], a33 = s3[sub + 96];

        v4f* __restrict__ d0 = (v4f*)(out + (size_t)(base + 0) * EMBED_DIM);
        v4f* __restrict__ d1 = (v4f*)(out + (size_t)(base + 1) * EMBED_DIM);
        v4f* __restrict__ d2 = (v4f*)(out + (size_t)(base + 2) * EMBED_DIM);
        v4f* __restrict__ d3 = (v4f*)(out + (size_t)(base + 3) * EMBED_DIM);

        __builtin_nontemporal_store(swap_pairs(a00), &d0[sub]);
        __builtin_nontemporal_store(swap_pairs(a01), &d0[sub + 32]);
        __builtin_nontemporal_store(swap_pairs(a02), &d0[sub + 64]);
        __builtin_nontemporal_store(swap_pairs(a03), &d0[sub + 96]);
        __builtin_nontemporal_store(swap_pairs(a10), &d1[sub]);
        __builtin_nontemporal_store(swap_pairs(a11), &d1[sub + 32]);
        __builtin_nontemporal_store(swap_pairs(a12), &d1[sub + 64]);
        __builtin_nontemporal_store(swap_pairs(a13), &d1[sub + 96]);
        __builtin_nontemporal_store(swap_pairs(a20), &d2[sub]);
        __builtin_nontemporal_store(swap_pairs(a21), &d2[sub + 32]);
        __builtin_nontemporal_store(swap_pairs(a22), &d2[sub + 64]);
        __builtin_nontemporal_store(swap_pairs(a23), &d2[sub + 96]);
        __builtin_nontemporal_store(swap_pairs(a30), &d3[sub]);
        __builtin_nontemporal_store(swap_pairs(a31), &d3[sub + 32]);
        __builtin_nontemporal_store(swap_pairs(a32), &d3[sub + 64]);
        __builtin_nontemporal_store(swap_pairs(a33), &d3[sub + 96]);
    } else {
        // Tail: fewer than POS_PER_GROUP positions left.
        for (int i = base; i < n_pos; ++i) {
            int p = positions[i];
            do_one_pos(sub, p, cache, out + (size_t)i * EMBED_DIM);
        }
    }
}

extern "C" void kernel_launch(void* const* d_in, const int* in_sizes, int n_in,
                              void* d_out, int out_size, void* d_ws, size_t ws_size,
                              hipStream_t stream) {
    const int*   positions = (const int*)d_in[0];
    const float* cache     = (const float*)d_in[1];
    float*       out       = (float*)d_out;

    int n_pos    = in_sizes[0];                              // 8 * 8192 = 65536
    int n_groups = (n_pos + POS_PER_GROUP - 1) / POS_PER_GROUP;
    int total_threads = n_groups * 32;                       // 524288 threads
    int block = 256;
    int grid  = (total_threads + block - 1) / block;         // 2048 blocks = 8/CU

    // Diagnostic: 4 idempotent launches -> dur_us ~= F + 4K. Slope gives the
    // kernel's true per-dispatch time, which top-5 rocprof can't show.
    for (int r = 0; r < N_LAUNCHES; ++r) {
        ScalarRoPEEmbedding_83769042141635_kernel<<<grid, block, 0, stream>>>(
            positions, cache, out, n_pos);
    }
}

// Round 3
// 167.729 us; speedup vs baseline: 1.6437x; 1.6437x over previous
//
#include <hip/hip_runtime.h>

// RoPE sin/cos table gather — V4: exact dedup via bucket-and-scatter.
//
// Diagnosis (R2 slope test): kernel K ~= 37.6 us, harness floor F ~= 125 us.
// K breakdown: 134 MB NT writes (20.6 us at the 6.5 TB/s fill ceiling) +
// ~17 us of read-stream contention (134 MB gather reads, 6.7x amplified over
// the 20 MB unique table). Fix: read each unique position row ONCE and
// scatter it to all duplicate output rows. Reads drop 134 -> ~23 MB.
//
// Pipeline (3 dispatches, all graph-capture-safe):
//   1. hipMemsetAsync: zero counts[10000] + overflow counter in d_ws
//   2. bucket_build:   pos_idx -> buckets[p][slot] via atomicAdd (65536 atomics)
//   3. scatter_rows:   one 64-lane wave per unique p: read row once (2 KB),
//                      pair-swap in-register, NT-store to every output row
//                      with that p. Writes unchanged: coalesced 1 KB/inst.
//
// Overflow safety: counts ~ Poisson(6.5); P(count >= 64) < 1e-40. Entries
// past MAX_DUP go to a capped overflow list handled by dedicated waves.
// If ws_size is too small, fall back to the verified V2 direct kernel.

#define EMBED_DIM 512
#define MAX_POSITION 10000
#define MAX_DUP 64
#define OV_CAP 2048

// ws layout (bytes):
//   [0, 40000)            counts[10000] (int)
//   [40000, 40004)        overflow counter (int)
//   [40064, 2600064)      buckets[10000][MAX_DUP] (int)
//   [2600064, 2608256)    overflow list[OV_CAP] (int)
#define WS_COUNTS_OFF   0
#define WS_OVCNT_OFF    40000
#define WS_MEMSET_BYTES 40064
#define WS_BUCKETS_OFF  40064
#define WS_OVLIST_OFF   2600064
#define WS_BYTES_NEEDED 2608256

typedef float v4f __attribute__((ext_vector_type(4)));
typedef int   v4i __attribute__((ext_vector_type(4)));

__device__ __forceinline__ v4f swap_pairs(v4f v) {
    // (sin0, cos0, sin1, cos1) -> (cos0, sin0, cos1, sin1)
    return (v4f){v.y, v.x, v.w, v.z};
}

// ---------------------------------------------------------------- dispatch 2
__global__ __launch_bounds__(256) void ScalarRoPEEmbedding_83769042141635_bucket(
    const int* __restrict__ positions, int n_pos,
    int* __restrict__ counts, int* __restrict__ ovf_cnt,
    int* __restrict__ buckets, int* __restrict__ ovf_list)
{
    int i = blockIdx.x * blockDim.x + threadIdx.x;
    if (i >= n_pos) return;
    int p = positions[i];
    int slot = atomicAdd(&counts[p], 1);
    if (slot < MAX_DUP) {
        buckets[p * MAX_DUP + slot] = i;
    } else {
        int o = atomicAdd(ovf_cnt, 1);
        if (o < OV_CAP) ovf_list[o] = i;
    }
}

// ---------------------------------------------------------------- dispatch 3
__global__ __launch_bounds__(256) void ScalarRoPEEmbedding_83769042141635_scatter(
    const int* __restrict__ positions,
    const float* __restrict__ cache,
    float* __restrict__ out,
    const int* __restrict__ counts, const int* __restrict__ ovf_cnt,
    const int* __restrict__ buckets, const int* __restrict__ ovf_list)
{
    int wave = (blockIdx.x * blockDim.x + threadIdx.x) >> 6;
    int lane = threadIdx.x & 63;

    if (wave < MAX_POSITION) {
        int p = wave;
        int cnt = counts[p];
        if (cnt == 0) return;
        if (cnt > MAX_DUP) cnt = MAX_DUP;

        // Read the 2 KB row ONCE: 64 lanes x 2 x 16 B, swap in-register.
        const v4f* __restrict__ src = (const v4f*)(cache + (size_t)p * EMBED_DIM);
        v4f wa = swap_pairs(src[lane]);
        v4f wb = swap_pairs(src[lane + 64]);

        // Scatter to every output row with this position value.
        const int* __restrict__ bk = buckets + p * MAX_DUP;
        for (int j = 0; j < cnt; ++j) {
            int row = bk[j];                      // same addr all lanes: broadcast
            v4f* __restrict__ dst = (v4f*)(out + (size_t)row * EMBED_DIM);
            __builtin_nontemporal_store(wa, &dst[lane]);
            __builtin_nontemporal_store(wb, &dst[lane + 64]);
        }
    } else {
        // Overflow entries: one row per wave.
        int o = wave - MAX_POSITION;
        int oc = *ovf_cnt;
        if (oc > OV_CAP) oc = OV_CAP;
        if (o >= oc) return;
        int row = ovf_list[o];
        int p = positions[row];
        const v4f* __restrict__ src = (const v4f*)(cache + (size_t)p * EMBED_DIM);
        v4f wa = swap_pairs(src[lane]);
        v4f wb = swap_pairs(src[lane + 64]);
        v4f* __restrict__ dst = (v4f*)(out + (size_t)row * EMBED_DIM);
        __builtin_nontemporal_store(wa, &dst[lane]);
        __builtin_nontemporal_store(wb, &dst[lane + 64]);
    }
}

// ------------------------------------------------- fallback (verified V2 path)
__global__ __launch_bounds__(256) void ScalarRoPEEmbedding_83769042141635_direct(
    const int* __restrict__ positions,
    const float* __restrict__ cache,
    float* __restrict__ out,
    int n_pos)
{
    int tid   = blockIdx.x * blockDim.x + threadIdx.x;
    int group = tid >> 5;
    int sub   = tid & 31;
    int base  = group * 4;
    if (base >= n_pos) return;

    if (base + 4 <= n_pos) {
        v4i p4 = *(const v4i*)(positions + base);
        const v4f* __restrict__ s0 = (const v4f*)(cache + (size_t)p4.x * EMBED_DIM);
        const v4f* __restrict__ s1 = (const v4f*)(cache + (size_t)p4.y * EMBED_DIM);
        const v4f* __restrict__ s2 = (const v4f*)(cache + (size_t)p4.z * EMBED_DIM);
        const v4f* __restrict__ s3 = (const v4f*)(cache + (size_t)p4.w * EMBED_DIM);
        v4f a00 = s0[sub], a01 = s0[sub + 32], a02 = s0[sub + 64], a03 = s0[sub + 96];
        v4f a10 = s1[sub], a11 = s1[sub + 32], a12 = s1[sub + 64], a13 = s1[sub + 96];
        v4f a20 = s2[sub], a21 = s2[sub + 32], a22 = s2[sub + 64], a23 = s2[sub + 96];
        v4f a30 = s3[sub], a31 = s3[sub + 32], a32 = s3[sub + 64], a33 = s3[sub + 96];
        v4f* __restrict__ d0 = (v4f*)(out + (size_t)(base + 0) * EMBED_DIM);
        v4f* __restrict__ d1 = (v4f*)(out + (size_t)(base + 1) * EMBED_DIM);
        v4f* __restrict__ d2 = (v4f*)(out + (size_t)(base + 2) * EMBED_DIM);
        v4f* __restrict__ d3 = (v4f*)(out + (size_t)(base + 3) * EMBED_DIM);
        __builtin_nontemporal_store(swap_pairs(a00), &d0[sub]);
        __builtin_nontemporal_store(swap_pairs(a01), &d0[sub + 32]);
        __builtin_nontemporal_store(swap_pairs(a02), &d0[sub + 64]);
        __builtin_nontemporal_store(swap_pairs(a03), &d0[sub + 96]);
        __builtin_nontemporal_store(swap_pairs(a10), &d1[sub]);
        __builtin_nontemporal_store(swap_pairs(a11), &d1[sub + 32]);
        __builtin_nontemporal_store(swap_pairs(a12), &d1[sub + 64]);
        __builtin_nontemporal_store(swap_pairs(a13), &d1[sub + 96]);
        __builtin_nontemporal_store(swap_pairs(a20), &d2[sub]);
        __builtin_nontemporal_store(swap_pairs(a21), &d2[sub + 32]);
        __builtin_nontemporal_store(swap_pairs(a22), &d2[sub + 64]);
        __builtin_nontemporal_store(swap_pairs(a23), &d2[sub + 96]);
        __builtin_nontemporal_store(swap_pairs(a30), &d3[sub]);
        __builtin_nontemporal_store(swap_pairs(a31), &d3[sub + 32]);
        __builtin_nontemporal_store(swap_pairs(a32), &d3[sub + 64]);
        __builtin_nontemporal_store(swap_pairs(a33), &d3[sub + 96]);
    } else {
        for (int i = base; i < n_pos; ++i) {
            int p = positions[i];
            const v4f* __restrict__ src = (const v4f*)(cache + (size_t)p * EMBED_DIM);
            v4f* __restrict__ dst       = (v4f*)(out + (size_t)i * EMBED_DIM);
            v4f v0 = src[sub];
            v4f v1 = src[sub + 32];
            v4f v2 = src[sub + 64];
            v4f v3 = src[sub + 96];
            __builtin_nontemporal_store(swap_pairs(v0), &dst[sub]);
            __builtin_nontemporal_store(swap_pairs(v1), &dst[sub + 32]);
            __builtin_nontemporal_store(swap_pairs(v2), &dst[sub + 64]);
            __builtin_nontemporal_store(swap_pairs(v3), &dst[sub + 96]);
        }
    }
}

extern "C" void kernel_launch(void* const* d_in, const int* in_sizes, int n_in,
                              void* d_out, int out_size, void* d_ws, size_t ws_size,
                              hipStream_t stream) {
    const int*   positions = (const int*)d_in[0];
    const float* cache     = (const float*)d_in[1];
    float*       out       = (float*)d_out;
    int n_pos = in_sizes[0];                                 // 8 * 8192 = 65536

    if (d_ws != nullptr && ws_size >= (size_t)WS_BYTES_NEEDED) {
        char* ws = (char*)d_ws;
        int* counts   = (int*)(ws + WS_COUNTS_OFF);
        int* ovf_cnt  = (int*)(ws + WS_OVCNT_OFF);
        int* buckets  = (int*)(ws + WS_BUCKETS_OFF);
        int* ovf_list = (int*)(ws + WS_OVLIST_OFF);

        // 1. zero counts + overflow counter
        hipMemsetAsync(d_ws, 0, WS_MEMSET_BYTES, stream);

        // 2. build buckets: 65536 atomics over 10000 L2-resident counters
        int blkA = 256;
        int grdA = (n_pos + blkA - 1) / blkA;
        ScalarRoPEEmbedding_83769042141635_bucket<<<grdA, blkA, 0, stream>>>(
            positions, n_pos, counts, ovf_cnt, buckets, ovf_list);

        // 3. scatter: one 64-lane wave per unique position (+ overflow waves)
        int n_waves = MAX_POSITION + OV_CAP;                 // 12048
        int blkB = 256;                                      // 4 waves/block
        int grdB = (n_waves * 64 + blkB - 1) / blkB;         // 3012 blocks
        ScalarRoPEEmbedding_83769042141635_scatter<<<grdB, blkB, 0, stream>>>(
            positions, cache, out, counts, ovf_cnt, buckets, ovf_list);
    } else {
        // Fallback: verified direct gather (V2).
        int n_groups = (n_pos + 3) / 4;
        int total_threads = n_groups * 32;
        int block = 256;
        int grid  = (total_threads + block - 1) / block;
        ScalarRoPEEmbedding_83769042141635_direct<<<grid, block, 0, stream>>>(
            positions, cache, out, n_pos);
    }
}

// Round 4
// 158.529 us; speedup vs baseline: 1.7391x; 1.0580x over previous
//
#include <hip/hip_runtime.h>

// RoPE sin/cos table gather — V5: single-factor A/B vs V2 — drop the NT hint.
//
// Evidence chain:
//   R2 slope test: direct kernel K ~= 37.6 us; harness floor F ~= 125 us.
//   R3 dedup test: scatter kernel (23 MB reads instead of 134 MB) ran the
//   SAME ~35 us -> read volume is NOT the bottleneck. Both kernels share
//   __builtin_nontemporal_store and both get ~3.6-3.9 TB/s effective write
//   BW, while the harness's fillBufferAligned (plain stores) hits 6.5 TB/s
//   in the same profile. Theory: the nt (no-allocate/evict-first) policy
//   defeats L2 write aggregation and caps streaming write BW. The original
//   rationale for NT ("keep table in L2") is moot: output 128 MiB + table
//   20 MiB fit in the 256 MiB L3 regardless.
//
// V5 = V2 body, identical in every respect except plain stores.
// Prediction: K -> ~24-28 us, dur_us ~= 149-154. If null, the remaining
// ~16 us is irreducible mixed-stream cost -> roofline.

#define EMBED_DIM 512
#define POS_PER_GROUP 4              // positions handled per 32-thread group

typedef float v4f __attribute__((ext_vector_type(4)));
typedef int   v4i __attribute__((ext_vector_type(4)));

__device__ __forceinline__ v4f swap_pairs(v4f v) {
    // (sin0, cos0, sin1, cos1) -> (cos0, sin0, cos1, sin1)
    return (v4f){v.y, v.x, v.w, v.z};
}

__global__ __launch_bounds__(256) void ScalarRoPEEmbedding_83769042141635_kernel(
    const int* __restrict__ positions,
    const float* __restrict__ cache,
    float* __restrict__ out,
    int n_pos)
{
    int tid   = blockIdx.x * blockDim.x + threadIdx.x;
    int group = tid >> 5;            // which group of POS_PER_GROUP positions
    int sub   = tid & 31;            // lane-within-group: owns 4 float4 per row
    int base  = group * POS_PER_GROUP;
    if (base >= n_pos) return;

    if (base + POS_PER_GROUP <= n_pos) {
        // Fast path: one 16B load for all 4 indices (base % 4 == 0 -> aligned).
        v4i p4 = *(const v4i*)(positions + base);

        const v4f* __restrict__ s0 = (const v4f*)(cache + (size_t)p4.x * EMBED_DIM);
        const v4f* __restrict__ s1 = (const v4f*)(cache + (size_t)p4.y * EMBED_DIM);
        const v4f* __restrict__ s2 = (const v4f*)(cache + (size_t)p4.z * EMBED_DIM);
        const v4f* __restrict__ s3 = (const v4f*)(cache + (size_t)p4.w * EMBED_DIM);

        // 16 independent loads in flight.
        v4f a00 = s0[sub], a01 = s0[sub + 32], a02 = s0[sub + 64], a03 = s0[sub + 96];
        v4f a10 = s1[sub], a11 = s1[sub + 32], a12 = s1[sub + 64], a13 = s1[sub + 96];
        v4f a20 = s2[sub], a21 = s2[sub + 32], a22 = s2[sub + 64], a23 = s2[sub + 96];
        v4f a30 = s3[sub], a31 = s3[sub + 32], a32 = s3[sub + 64], a33 = s3[sub + 96];

        v4f* __restrict__ d0 = (v4f*)(out + (size_t)(base + 0) * EMBED_DIM);
        v4f* __restrict__ d1 = (v4f*)(out + (size_t)(base + 1) * EMBED_DIM);
        v4f* __restrict__ d2 = (v4f*)(out + (size_t)(base + 2) * EMBED_DIM);
        v4f* __restrict__ d3 = (v4f*)(out + (size_t)(base + 3) * EMBED_DIM);

        // Plain (cache-allocating) stores — the ONLY change vs V2.
        d0[sub]      = swap_pairs(a00);
        d0[sub + 32] = swap_pairs(a01);
        d0[sub + 64] = swap_pairs(a02);
        d0[sub + 96] = swap_pairs(a03);
        d1[sub]      = swap_pairs(a10);
        d1[sub + 32] = swap_pairs(a11);
        d1[sub + 64] = swap_pairs(a12);
        d1[sub + 96] = swap_pairs(a13);
        d2[sub]      = swap_pairs(a20);
        d2[sub + 32] = swap_pairs(a21);
        d2[sub + 64] = swap_pairs(a22);
        d2[sub + 96] = swap_pairs(a23);
        d3[sub]      = swap_pairs(a30);
        d3[sub + 32] = swap_pairs(a31);
        d3[sub + 64] = swap_pairs(a32);
        d3[sub + 96] = swap_pairs(a33);
    } else {
        // Tail: fewer than POS_PER_GROUP positions left.
        for (int i = base; i < n_pos; ++i) {
            int p = positions[i];
            const v4f* __restrict__ src = (const v4f*)(cache + (size_t)p * EMBED_DIM);
            v4f* __restrict__ dst       = (v4f*)(out + (size_t)i * EMBED_DIM);
            v4f v0 = src[sub];
            v4f v1 = src[sub + 32];
            v4f v2 = src[sub + 64];
            v4f v3 = src[sub + 96];
            dst[sub]      = swap_pairs(v0);
            dst[sub + 32] = swap_pairs(v1);
            dst[sub + 64] = swap_pairs(v2);
            dst[sub + 96] = swap_pairs(v3);
        }
    }
}

extern "C" void kernel_launch(void* const* d_in, const int* in_sizes, int n_in,
                              void* d_out, int out_size, void* d_ws, size_t ws_size,
                              hipStream_t stream) {
    const int*   positions = (const int*)d_in[0];
    const float* cache     = (const float*)d_in[1];
    float*       out       = (float*)d_out;

    int n_pos    = in_sizes[0];                              // 8 * 8192 = 65536
    int n_groups = (n_pos + POS_PER_GROUP - 1) / POS_PER_GROUP;
    int total_threads = n_groups * 32;                       // 524288 threads
    int block = 256;
    int grid  = (total_threads + block - 1) / block;         // 2048 blocks = 8/CU

    ScalarRoPEEmbedding_83769042141635_kernel<<<grid, block, 0, stream>>>(
        positions, cache, out, n_pos);
}